// Round 11
// baseline (1126.130 us; speedup 1.0000x reference)
//
#include <hip/hip_runtime.h>
#include <math.h>

#define N_ROWS 65536

typedef short short8 __attribute__((ext_vector_type(8)));
typedef float f32x4 __attribute__((ext_vector_type(4)));

__device__ __forceinline__ float gelu_f(float x) {
  float x3 = x * x * x;
  float t = tanhf(0.7978845608028654f * (x + 0.044715f * x3));
  return 0.5f * x * (1.0f + t);
}

__device__ __forceinline__ unsigned short f2bf(float f) {
  unsigned u = __float_as_uint(f);
  unsigned r = u + 0x7fffu + ((u >> 16) & 1u);
  return (unsigned short)(r >> 16);
}
__device__ __forceinline__ float bf2f(unsigned short h) {
  return __uint_as_float(((unsigned)h) << 16);
}

// RNE split (one-time weight prep)
__device__ __forceinline__ void split3(float v, unsigned short& p0,
                                       unsigned short& p1, unsigned short& p2) {
  p0 = f2bf(v);
  float r = v - bf2f(p0);
  p1 = f2bf(r);
  r -= bf2f(p1);
  p2 = f2bf(r);
}

// cheap split: round-half-up planes 0/1 (<=0.5 ulp, exact residuals), RNE last
__device__ __forceinline__ void split3f(float v, unsigned short& p0,
                                        unsigned short& p1, unsigned short& p2) {
  unsigned u = __float_as_uint(v);
  unsigned h0 = (u + 0x8000u) & 0xffff0000u;
  float r = v - __uint_as_float(h0);
  unsigned u1 = __float_as_uint(r);
  unsigned h1 = (u1 + 0x8000u) & 0xffff0000u;
  float r2 = r - __uint_as_float(h1);
  p0 = (unsigned short)(h0 >> 16);
  p1 = (unsigned short)(h1 >> 16);
  p2 = f2bf(r2);
}

// 2-plane split: residual after 2 planes <= 2^-17 * |v|
__device__ __forceinline__ void split2f(float v, unsigned short& p0,
                                        unsigned short& p1) {
  unsigned u = __float_as_uint(v);
  unsigned h0 = (u + 0x8000u) & 0xffff0000u;
  float r = v - __uint_as_float(h0);
  p0 = (unsigned short)(h0 >> 16);
  p1 = f2bf(r);
}

__device__ __forceinline__ f32x4 mfma16(short8 a, short8 b, f32x4 c) {
  return __builtin_amdgcn_mfma_f32_16x16x32_bf16(a, b, c, 0, 0, 0);
}

// ---------------- enc0: P_planes = split3(gelu(A @ W + b)) ----------------
__global__ __launch_bounds__(256) void gemm_enc0_split(
    const float* __restrict__ A, const float* __restrict__ W,
    const float* __restrict__ bias, unsigned short* __restrict__ P,
    size_t aps, int din, int dout) {
  __shared__ float As[16][132];
  __shared__ float Ws[16][132];
  int t = threadIdx.x;
  int tx = t & 15, ty = t >> 4;
  int c0 = blockIdx.x * 128;
  int r0 = blockIdx.y * 128;

  float acc[8][8];
#pragma unroll
  for (int i = 0; i < 8; ++i)
#pragma unroll
    for (int j = 0; j < 8; ++j) acc[i][j] = 0.0f;

  int kchunks = din >> 4;
  for (int kc = 0; kc < kchunks; ++kc) {
    int k0 = kc << 4;
    __syncthreads();
#pragma unroll
    for (int it = 0; it < 2; ++it) {
      int id = t + it * 256;
      int r = id >> 2;
      int kq = (id & 3) * 4;
      float4 v = *(const float4*)&A[(long)(r0 + r) * din + (k0 + kq)];
      As[kq + 0][r] = v.x; As[kq + 1][r] = v.y;
      As[kq + 2][r] = v.z; As[kq + 3][r] = v.w;
      int k = id >> 5;
      int cq = (id & 31) * 4;
      float4 w = *(const float4*)&W[(long)(k0 + k) * dout + (c0 + cq)];
      *(float4*)&Ws[k][cq] = w;
    }
    __syncthreads();
#pragma unroll
    for (int k = 0; k < 16; ++k) {
      float av[8], bv[8];
      *(float4*)&av[0] = *(const float4*)&As[k][ty * 4];
      *(float4*)&av[4] = *(const float4*)&As[k][ty * 4 + 64];
      *(float4*)&bv[0] = *(const float4*)&Ws[k][tx * 4];
      *(float4*)&bv[4] = *(const float4*)&Ws[k][tx * 4 + 64];
#pragma unroll
      for (int i = 0; i < 8; ++i)
#pragma unroll
        for (int j = 0; j < 8; ++j)
          acc[i][j] = fmaf(av[i], bv[j], acc[i][j]);
    }
  }

  float bbv[8];
  *(float4*)&bbv[0] = *(const float4*)&bias[c0 + tx * 4];
  *(float4*)&bbv[4] = *(const float4*)&bias[c0 + tx * 4 + 64];
#pragma unroll
  for (int i = 0; i < 8; ++i) {
    long row = r0 + ty * 4 + (i & 3) + ((i >> 2) * 64);
    unsigned short s0[8], s1[8], s2[8];
#pragma unroll
    for (int j = 0; j < 8; ++j) {
      float v = gelu_f(acc[i][j] + bbv[j]);
      split3f(v, s0[j], s1[j], s2[j]);
    }
    size_t b = (size_t)row * dout + c0 + tx * 4;
    ushort4 w;
    w.x = s0[0]; w.y = s0[1]; w.z = s0[2]; w.w = s0[3];
    *(ushort4*)&P[b] = w;
    w.x = s0[4]; w.y = s0[5]; w.z = s0[6]; w.w = s0[7];
    *(ushort4*)&P[b + 64] = w;
    w.x = s1[0]; w.y = s1[1]; w.z = s1[2]; w.w = s1[3];
    *(ushort4*)&P[aps + b] = w;
    w.x = s1[4]; w.y = s1[5]; w.z = s1[6]; w.w = s1[7];
    *(ushort4*)&P[aps + b + 64] = w;
    w.x = s2[0]; w.y = s2[1]; w.z = s2[2]; w.w = s2[3];
    *(ushort4*)&P[2 * aps + b] = w;
    w.x = s2[4]; w.y = s2[5]; w.z = s2[6]; w.w = s2[7];
    *(ushort4*)&P[2 * aps + b + 64] = w;
  }
}

// ---------------- fp32 GEMM 64x64 (small-M precompute) ----------------
template <bool GELU>
__global__ __launch_bounds__(256) void gemm64_kernel(
    const float* __restrict__ A, const float* __restrict__ W,
    const float* __restrict__ bias, float* __restrict__ C,
    int din, int dout) {
  __shared__ float As[16][68];
  __shared__ float Ws[16][68];
  int t = threadIdx.x;
  int tx = t & 15, ty = t >> 4;
  int c0 = blockIdx.x * 64;
  int r0 = blockIdx.y * 64;

  float acc[4][4];
#pragma unroll
  for (int i = 0; i < 4; ++i)
#pragma unroll
    for (int j = 0; j < 4; ++j) acc[i][j] = 0.0f;

  int kchunks = din >> 4;
  for (int kc = 0; kc < kchunks; ++kc) {
    int k0 = kc << 4;
    __syncthreads();
    {
      int r = t >> 2, kq = (t & 3) * 4;
      float4 v = *(const float4*)&A[(long)(r0 + r) * din + (k0 + kq)];
      As[kq + 0][r] = v.x; As[kq + 1][r] = v.y;
      As[kq + 2][r] = v.z; As[kq + 3][r] = v.w;
      int k = t >> 4, cq = (t & 15) * 4;
      *(float4*)&Ws[k][cq] = *(const float4*)&W[(long)(k0 + k) * dout + (c0 + cq)];
    }
    __syncthreads();
#pragma unroll
    for (int k = 0; k < 16; ++k) {
      float av[4], bv[4];
      *(float4*)&av[0] = *(const float4*)&As[k][ty * 4];
      *(float4*)&bv[0] = *(const float4*)&Ws[k][tx * 4];
#pragma unroll
      for (int i = 0; i < 4; ++i)
#pragma unroll
        for (int j = 0; j < 4; ++j)
          acc[i][j] = fmaf(av[i], bv[j], acc[i][j]);
    }
  }

  float4 bb = *(const float4*)&bias[c0 + tx * 4];
#pragma unroll
  for (int i = 0; i < 4; ++i) {
    long row = r0 + ty * 4 + i;
    float o[4];
    o[0] = acc[i][0] + bb.x; o[1] = acc[i][1] + bb.y;
    o[2] = acc[i][2] + bb.z; o[3] = acc[i][3] + bb.w;
    if (GELU) {
      o[0] = gelu_f(o[0]); o[1] = gelu_f(o[1]);
      o[2] = gelu_f(o[2]); o[3] = gelu_f(o[3]);
    }
    *(float4*)&C[row * dout + c0 + tx * 4] = *(float4*)&o[0];
  }
}

// ---- W [K][N] fp32 -> 3-plane MFMA-fragment-major Bfrag ----
__global__ void frag_pack_kernel(const float* __restrict__ W,
                                 unsigned short* __restrict__ Bf,
                                 int K, int N) {
  int l = threadIdx.x;
  int m = l & 15, q = l >> 4;
  int cb = blockIdx.x, kb = blockIdx.y;
  unsigned short s0[8], s1[8], s2[8];
#pragma unroll
  for (int j = 0; j < 8; ++j) {
    float v = W[(long)(kb * 32 + q * 8 + j) * N + cb * 16 + m];
    split3(v, s0[j], s1[j], s2[j]);
  }
  size_t base = ((size_t)cb * (K / 32) + kb) * 3 * 512;
  *(short8*)&Bf[base + 0 * 512 + l * 8] = *(short8*)s0;
  *(short8*)&Bf[base + 1 * 512 + l * 8] = *(short8*)s1;
  *(short8*)&Bf[base + 2 * 512 + l * 8] = *(short8*)s2;
}

// ---- cbn [1024][256] fp32 -> 2-plane fragment-major (B = cbn^T) ----
__global__ void frag_pack2_t(const float* __restrict__ cbn,
                             unsigned short* __restrict__ Bf) {
  int l = threadIdx.x;
  int m = l & 15, q = l >> 4;
  int cb = blockIdx.x, kb = blockIdx.y;
  unsigned short s0[8], s1[8];
  const float* src = cbn + (long)(cb * 16 + m) * 256 + kb * 32 + q * 8;
#pragma unroll
  for (int j = 0; j < 8; ++j) split2f(src[j], s0[j], s1[j]);
  size_t base = ((size_t)(cb * 8 + kb) * 2) * 512;
  *(short8*)&Bf[base + l * 8] = *(short8*)s0;
  *(short8*)&Bf[base + 512 + l * 8] = *(short8*)s1;
}

// ---------------- bf16x3-split MFMA GEMM, dbuf LDS + early A-issue --------
// A global loads for tile kb+1 issued at the TOP of the MFMA phase (same
// barrier region) so HBM latency hides under the 96-MFMA block; ds_writes
// stay at the bottom. Bit-identical numerics.
template <bool GELU>
__global__ __launch_bounds__(256) void mfma3_gemm(
    const unsigned short* __restrict__ Ap, size_t aps,
    const unsigned short* __restrict__ Bf,
    const float* __restrict__ bias, float* __restrict__ C,
    int K, int dout) {
  // 2 x [p 3][wrb 2][x 4][granule 64][8 shorts] = 49152 B
  __shared__ unsigned short A_f[2][3 * 2 * 4 * 512];
  int t = threadIdx.x;
  int lane = t & 63, wave = t >> 6;
  int q = lane >> 4, m = lane & 15;
  int wrb = wave >> 1;
  int wr = wrb * 64, wc = (wave & 1) * 64;

  // XCD-aware remap: contiguous row-panel runs per XCD (L2 locality).
  int gx = gridDim.x, tot = gx * gridDim.y;
  int lin = blockIdx.y * gx + blockIdx.x;
  if (!(tot & 7)) lin = (lin & 7) * (tot >> 3) + (lin >> 3);
  int bx = lin % gx, by = lin / gx;

  long r0 = (long)by * 128;
  int c0 = bx * 128;
  int kchunks = K >> 5;

  f32x4 acc[4][4];
#pragma unroll
  for (int i = 0; i < 4; ++i)
#pragma unroll
    for (int j = 0; j < 4; ++j) acc[i][j] = (f32x4){0.f, 0.f, 0.f, 0.f};

  int rs = t >> 1, hs = (t & 1) * 16;
  const unsigned short* a0p = Ap + (size_t)(r0 + rs) * K + hs;
  const unsigned short* a1p = a0p + aps;
  const unsigned short* a2p = a0p + 2 * aps;
  int cb0 = (c0 + wc) >> 4;
  // writer-side fragment coordinates
  int xw = (rs >> 4) & 3, wrbw = rs >> 6, mw = rs & 15;
  int g0 = ((t & 1) * 2 + 0) * 16 + mw;
  int g1 = ((t & 1) * 2 + 1) * 16 + mw;
  int wb0 = (0 * 2 + wrbw) * 4 + xw;
  int wb1 = (1 * 2 + wrbw) * 4 + xw;
  int wb2 = (2 * 2 + wrbw) * 4 + xw;

  // prologue: stage tile 0 into buffer 0
  {
    uint4 u00 = *(const uint4*)(a0p);
    uint4 u01 = *(const uint4*)(a0p + 8);
    uint4 u10 = *(const uint4*)(a1p);
    uint4 u11 = *(const uint4*)(a1p + 8);
    uint4 u20 = *(const uint4*)(a2p);
    uint4 u21 = *(const uint4*)(a2p + 8);
    *(uint4*)&A_f[0][wb0 * 512 + g0 * 8] = u00;
    *(uint4*)&A_f[0][wb0 * 512 + g1 * 8] = u01;
    *(uint4*)&A_f[0][wb1 * 512 + g0 * 8] = u10;
    *(uint4*)&A_f[0][wb1 * 512 + g1 * 8] = u11;
    *(uint4*)&A_f[0][wb2 * 512 + g0 * 8] = u20;
    *(uint4*)&A_f[0][wb2 * 512 + g1 * 8] = u21;
  }
  __syncthreads();

  int cur = 0;
  for (int kb = 0; kb < kchunks; ++kb) {
    short8 af[3][4];
#pragma unroll
    for (int p = 0; p < 3; ++p)
#pragma unroll
      for (int x = 0; x < 4; ++x)
        af[p][x] =
            *(const short8*)&A_f[cur][((p * 2 + wrb) * 4 + x) * 512 + lane * 8];
    // early-issue A loads for kb+1 (latency hides under MFMA block below)
    uint4 u00, u01, u10, u11, u20, u21;
    bool more = (kb + 1 < kchunks);
    if (more) {
      int kt = (kb + 1) << 5;
      u00 = *(const uint4*)(a0p + kt);
      u01 = *(const uint4*)(a0p + kt + 8);
      u10 = *(const uint4*)(a1p + kt);
      u11 = *(const uint4*)(a1p + kt + 8);
      u20 = *(const uint4*)(a2p + kt);
      u21 = *(const uint4*)(a2p + kt + 8);
    }
#pragma unroll
    for (int ct = 0; ct < 4; ++ct) {
      size_t fb = ((size_t)(cb0 + ct) * kchunks + kb) * 3 * 512 + lane * 8;
      short8 b0 = *(const short8*)&Bf[fb];
      short8 b1 = *(const short8*)&Bf[fb + 512];
      short8 b2 = *(const short8*)&Bf[fb + 1024];
#pragma unroll
      for (int rt = 0; rt < 4; ++rt) {
        acc[rt][ct] = mfma16(af[0][rt], b0, acc[rt][ct]);
        acc[rt][ct] = mfma16(af[0][rt], b1, acc[rt][ct]);
        acc[rt][ct] = mfma16(af[1][rt], b0, acc[rt][ct]);
        acc[rt][ct] = mfma16(af[0][rt], b2, acc[rt][ct]);
        acc[rt][ct] = mfma16(af[1][rt], b1, acc[rt][ct]);
        acc[rt][ct] = mfma16(af[2][rt], b0, acc[rt][ct]);
      }
    }
    // stage tile kb+1 into the other buffer (data already in regs)
    if (more) {
      int nb = cur ^ 1;
      *(uint4*)&A_f[nb][wb0 * 512 + g0 * 8] = u00;
      *(uint4*)&A_f[nb][wb0 * 512 + g1 * 8] = u01;
      *(uint4*)&A_f[nb][wb1 * 512 + g0 * 8] = u10;
      *(uint4*)&A_f[nb][wb1 * 512 + g1 * 8] = u11;
      *(uint4*)&A_f[nb][wb2 * 512 + g0 * 8] = u20;
      *(uint4*)&A_f[nb][wb2 * 512 + g1 * 8] = u21;
    }
    __syncthreads();
    cur ^= 1;
  }

#pragma unroll
  for (int ct = 0; ct < 4; ++ct) {
    long col = c0 + wc + ct * 16 + m;
    float bv = bias[col];
#pragma unroll
    for (int rt = 0; rt < 4; ++rt) {
      long rowb = r0 + wr + rt * 16 + q * 4;
#pragma unroll
      for (int r = 0; r < 4; ++r) {
        float v = acc[rt][ct][r] + bv;
        if (GELU) v = gelu_f(v);
        C[(rowb + r) * dout + col] = v;
      }
    }
  }
}

// ---------------- enc2 + rownorm fused, dbuf LDS + early A-issue ----------
__global__ __launch_bounds__(256) void mfma3_norm(
    const float* __restrict__ A, const unsigned short* __restrict__ Bf,
    const float* __restrict__ bias, float* __restrict__ z_e,
    float* __restrict__ ze2) {
  __shared__ unsigned short A_f[2][3 * 4 * 512];  // 2 x 12 KB
  __shared__ float S[64][4];
  __shared__ float Sinv[64];
  const int K = 1024, kchunks = 32;
  int t = threadIdx.x;
  int lane = t & 63, wave = t >> 6;  // wave = col quarter
  int q = lane >> 4, m = lane & 15;
  long r0 = (long)blockIdx.x * 64;

  f32x4 acc[4][4];
#pragma unroll
  for (int i = 0; i < 4; ++i)
#pragma unroll
    for (int j = 0; j < 4; ++j) acc[i][j] = (f32x4){0.f, 0.f, 0.f, 0.f};

  int rs = t >> 2, kq = t & 3;
  const float* aptr = A + (r0 + rs) * K + kq * 8;
  int xw = rs >> 4, mw = rs & 15;
  int gw = kq * 16 + mw;
  int wb0 = 0 * 4 + xw, wb1 = 1 * 4 + xw, wb2 = 2 * 4 + xw;
  int cb0 = wave * 4;

  // prologue: stage k-tile 0 into buffer 0
  {
    float fv[8];
    *(float4*)&fv[0] = *(const float4*)(aptr);
    *(float4*)&fv[4] = *(const float4*)(aptr + 4);
    unsigned short a0[8], a1[8], a2[8];
#pragma unroll
    for (int i = 0; i < 8; ++i) split3f(fv[i], a0[i], a1[i], a2[i]);
    *(uint4*)&A_f[0][wb0 * 512 + gw * 8] = *(uint4*)a0;
    *(uint4*)&A_f[0][wb1 * 512 + gw * 8] = *(uint4*)a1;
    *(uint4*)&A_f[0][wb2 * 512 + gw * 8] = *(uint4*)a2;
  }
  __syncthreads();

  int cur = 0;
  for (int kb = 0; kb < kchunks; ++kb) {
    short8 af[3][4];
#pragma unroll
    for (int p = 0; p < 3; ++p)
#pragma unroll
      for (int x = 0; x < 4; ++x)
        af[p][x] = *(const short8*)&A_f[cur][(p * 4 + x) * 512 + lane * 8];
    // early-issue A loads for kb+1; split+write deferred past MFMA block
    float fv[8];
    bool more = (kb + 1 < kchunks);
    if (more) {
      *(float4*)&fv[0] = *(const float4*)(aptr + ((kb + 1) << 5));
      *(float4*)&fv[4] = *(const float4*)(aptr + ((kb + 1) << 5) + 4);
    }
#pragma unroll
    for (int ct = 0; ct < 4; ++ct) {
      size_t fb = ((size_t)(cb0 + ct) * kchunks + kb) * 3 * 512 + lane * 8;
      short8 b0 = *(const short8*)&Bf[fb];
      short8 b1 = *(const short8*)&Bf[fb + 512];
      short8 b2 = *(const short8*)&Bf[fb + 1024];
#pragma unroll
      for (int rt = 0; rt < 4; ++rt) {
        acc[rt][ct] = mfma16(af[0][rt], b0, acc[rt][ct]);
        acc[rt][ct] = mfma16(af[0][rt], b1, acc[rt][ct]);
        acc[rt][ct] = mfma16(af[1][rt], b0, acc[rt][ct]);
        acc[rt][ct] = mfma16(af[0][rt], b2, acc[rt][ct]);
        acc[rt][ct] = mfma16(af[1][rt], b1, acc[rt][ct]);
        acc[rt][ct] = mfma16(af[2][rt], b0, acc[rt][ct]);
      }
    }
    if (more) {
      unsigned short a0[8], a1[8], a2[8];
#pragma unroll
      for (int i = 0; i < 8; ++i) split3f(fv[i], a0[i], a1[i], a2[i]);
      int nb = cur ^ 1;
      *(uint4*)&A_f[nb][wb0 * 512 + gw * 8] = *(uint4*)a0;
      *(uint4*)&A_f[nb][wb1 * 512 + gw * 8] = *(uint4*)a1;
      *(uint4*)&A_f[nb][wb2 * 512 + gw * 8] = *(uint4*)a2;
    }
    __syncthreads();
    cur ^= 1;
  }

  // bias add (no gelu on last encoder layer)
#pragma unroll
  for (int ct = 0; ct < 4; ++ct) {
    float bv = bias[wave * 64 + ct * 16 + m];
#pragma unroll
    for (int rt = 0; rt < 4; ++rt)
#pragma unroll
      for (int r = 0; r < 4; ++r) acc[rt][ct][r] += bv;
  }

  // per-row sumsq partial over this wave's 64 cols
#pragma unroll
  for (int rt = 0; rt < 4; ++rt)
#pragma unroll
    for (int r = 0; r < 4; ++r) {
      float s = acc[rt][0][r] * acc[rt][0][r] + acc[rt][1][r] * acc[rt][1][r] +
                acc[rt][2][r] * acc[rt][2][r] + acc[rt][3][r] * acc[rt][3][r];
#pragma unroll
      for (int off = 1; off <= 8; off <<= 1) s += __shfl_xor(s, off);
      if (m == 0) S[rt * 16 + q * 4 + r][wave] = s;
    }
  __syncthreads();
  if (t < 64) {
    float s = S[t][0] + S[t][1] + S[t][2] + S[t][3];
    float den = sqrtf(s) + 1e-8f;
    Sinv[t] = 1.0f / den;
    ze2[r0 + t] = s / (den * den);
  }
  __syncthreads();
#pragma unroll
  for (int rt = 0; rt < 4; ++rt)
#pragma unroll
    for (int r = 0; r < 4; ++r) {
      int rl = rt * 16 + q * 4 + r;
      float inv = Sinv[rl];
#pragma unroll
      for (int ct = 0; ct < 4; ++ct)
        z_e[(r0 + rl) * 256 + wave * 64 + ct * 16 + m] = acc[rt][ct][r] * inv;
    }
}

// ---------------- 2-plane bf16-split MFMA distances: top-2 of z_e . cb^T ----
// B fragments register-double-buffered one kb ahead (R10 win).
__global__ __launch_bounds__(256) void dist2_mfma(
    const float* __restrict__ z_e, const unsigned short* __restrict__ cbf,
    int* __restrict__ idxc, int* __restrict__ fixcnt, int* __restrict__ fixlist) {
  // [p 2][kb 8][x 4][granule 64][8 shorts] = 64 KB
  __shared__ unsigned short A_f[2 * 8 * 4 * 512];
  __shared__ float Lv1[64][4], Lv2[64][4];
  __shared__ int Lc1[64][4];
  int t = threadIdx.x;
  int lane = t & 63, wave = t >> 6;
  int q = lane >> 4, m = lane & 15;
  long r0 = (long)blockIdx.x * 64;

#pragma unroll
  for (int it = 0; it < 4; ++it) {
    int kb = it * 2 + (t >> 7);
    int rs = (t & 127) >> 1, hs = (t & 1) * 16;
    const float* ap = z_e + (r0 + rs) * 256 + kb * 32 + hs;
    float fv[16];
    *(float4*)&fv[0] = *(const float4*)(ap + 0);
    *(float4*)&fv[4] = *(const float4*)(ap + 4);
    *(float4*)&fv[8] = *(const float4*)(ap + 8);
    *(float4*)&fv[12] = *(const float4*)(ap + 12);
    unsigned short a0[16], a1[16];
#pragma unroll
    for (int i = 0; i < 16; ++i) split2f(fv[i], a0[i], a1[i]);
    int x = rs >> 4, mm = rs & 15;
    int ga = ((t & 1) * 2 + 0) * 16 + mm;
    int gb = ((t & 1) * 2 + 1) * 16 + mm;
    int b0 = ((0 * 8 + kb) * 4 + x) * 512;
    int b1 = ((1 * 8 + kb) * 4 + x) * 512;
    *(uint4*)&A_f[b0 + ga * 8] = ((uint4*)a0)[0];
    *(uint4*)&A_f[b0 + gb * 8] = ((uint4*)a0)[1];
    *(uint4*)&A_f[b1 + ga * 8] = ((uint4*)a1)[0];
    *(uint4*)&A_f[b1 + gb * 8] = ((uint4*)a1)[1];
  }
  __syncthreads();

  float v1[4][4], v2[4][4];
  int c1[4][4];
#pragma unroll
  for (int i = 0; i < 4; ++i)
#pragma unroll
    for (int j = 0; j < 4; ++j) { v1[i][j] = -3.4e38f; v2[i][j] = -3.4e38f; c1[i][j] = 0; }

  // prefetch B fragments for (ctp=0, kb=0)
  short8 bf0[4], bf1[4];
#pragma unroll
  for (int cs = 0; cs < 4; ++cs) {
    int cb = 0 * 16 + (cs >> 1) * 8 + wave * 2 + (cs & 1);
    size_t fb = ((size_t)(cb * 8 + 0) * 2) * 512 + lane * 8;
    bf0[cs] = *(const short8*)&cbf[fb];
    bf1[cs] = *(const short8*)&cbf[fb + 512];
  }

  for (int ctp = 0; ctp < 4; ++ctp) {
    f32x4 acc[4][4];
#pragma unroll
    for (int i = 0; i < 4; ++i)
#pragma unroll
      for (int j = 0; j < 4; ++j) acc[i][j] = (f32x4){0.f, 0.f, 0.f, 0.f};

    for (int kb = 0; kb < 8; ++kb) {
      // issue next iteration's B loads (consumed after this MFMA block)
      short8 nb0[4], nb1[4];
      int kbn = (kb + 1) & 7;
      int ctpn = (kb == 7) ? ctp + 1 : ctp;
      if (ctpn < 4) {
#pragma unroll
        for (int cs = 0; cs < 4; ++cs) {
          int cb = ctpn * 16 + (cs >> 1) * 8 + wave * 2 + (cs & 1);
          size_t fb = ((size_t)(cb * 8 + kbn) * 2) * 512 + lane * 8;
          nb0[cs] = *(const short8*)&cbf[fb];
          nb1[cs] = *(const short8*)&cbf[fb + 512];
        }
      }
      short8 af0[4], af1[4];
#pragma unroll
      for (int rt = 0; rt < 4; ++rt) {
        af0[rt] = *(const short8*)&A_f[((0 * 8 + kb) * 4 + rt) * 512 + lane * 8];
        af1[rt] = *(const short8*)&A_f[((1 * 8 + kb) * 4 + rt) * 512 + lane * 8];
      }
#pragma unroll
      for (int rt = 0; rt < 4; ++rt)
#pragma unroll
        for (int cs = 0; cs < 4; ++cs) {
          acc[rt][cs] = mfma16(af0[rt], bf0[cs], acc[rt][cs]);
          acc[rt][cs] = mfma16(af0[rt], bf1[cs], acc[rt][cs]);
          acc[rt][cs] = mfma16(af1[rt], bf0[cs], acc[rt][cs]);
        }
      if (ctpn < 4) {
#pragma unroll
        for (int cs = 0; cs < 4; ++cs) { bf0[cs] = nb0[cs]; bf1[cs] = nb1[cs]; }
      }
    }
#pragma unroll
    for (int rt = 0; rt < 4; ++rt)
#pragma unroll
      for (int cs = 0; cs < 4; ++cs) {
        int colb = ctp * 256 + (cs >> 1) * 128 + wave * 32 + (cs & 1) * 16 + m;
#pragma unroll
        for (int r = 0; r < 4; ++r) {
          float v = acc[rt][cs][r];
          float nv2 = fmaxf(v2[rt][r], fminf(v, v1[rt][r]));
          if (v > v1[rt][r]) { c1[rt][r] = colb; v1[rt][r] = v; }
          v2[rt][r] = nv2;
        }
      }
  }

#pragma unroll
  for (int off = 1; off <= 8; off <<= 1) {
#pragma unroll
    for (int rt = 0; rt < 4; ++rt)
#pragma unroll
      for (int r = 0; r < 4; ++r) {
        float ov1 = __shfl_xor(v1[rt][r], off);
        float ov2 = __shfl_xor(v2[rt][r], off);
        int oc1 = __shfl_xor(c1[rt][r], off);
        float nv2 = fmaxf(fmaxf(v2[rt][r], ov2), fminf(v1[rt][r], ov1));
        if (ov1 > v1[rt][r] || (ov1 == v1[rt][r] && oc1 < c1[rt][r])) {
          v1[rt][r] = ov1; c1[rt][r] = oc1;
        }
        v2[rt][r] = nv2;
      }
  }
  if (m == 0) {
#pragma unroll
    for (int rt = 0; rt < 4; ++rt)
#pragma unroll
      for (int r = 0; r < 4; ++r) {
        int rloc = rt * 16 + q * 4 + r;
        Lv1[rloc][wave] = v1[rt][r];
        Lv2[rloc][wave] = v2[rt][r];
        Lc1[rloc][wave] = c1[rt][r];
      }
  }
  __syncthreads();
  if (t < 64) {
    float a1 = Lv1[t][0], a2 = Lv2[t][0];
    int ac = Lc1[t][0];
#pragma unroll
    for (int w = 1; w < 4; ++w) {
      float b1 = Lv1[t][w], b2 = Lv2[t][w];
      int bc = Lc1[t][w];
      float n2 = fmaxf(fmaxf(a2, b2), fminf(a1, b1));
      if (b1 > a1 || (b1 == a1 && bc < ac)) { a1 = b1; ac = bc; }
      a2 = n2;
    }
    idxc[r0 + t] = ac;
    if (a1 - a2 < 5.0e-4f) {
      int p = atomicAdd(fixcnt, 1);
      fixlist[p] = r0 + t;
    }
  }
}

// ---------------- fp32 exact argmin fixup, code-parallel ----------------
__global__ __launch_bounds__(256) void fixup_part(
    const float* __restrict__ z_e, const float* __restrict__ cbn,
    const float* __restrict__ ze2, const float* __restrict__ cb2,
    const int* __restrict__ fixlist, const int* __restrict__ fixcnt,
    float* __restrict__ fixbv, int* __restrict__ fixbc) {
  int cnt = *fixcnt;
  int r0 = blockIdx.y * 128;
  if (r0 >= cnt) return;
  int ctile = blockIdx.x;
  int c0 = ctile * 128;
  __shared__ float As[16][132];
  __shared__ float Ws[16][132];
  __shared__ float rv[128][17];
  __shared__ int rc[128][17];
  __shared__ int rows_l[128];
  int t = threadIdx.x, tx = t & 15, ty = t >> 4;

  if (t < 128) rows_l[t] = fixlist[(r0 + t < cnt) ? (r0 + t) : 0];
  __syncthreads();

  float bestv[8];
  int bestc[8];
  float myze2[8];
#pragma unroll
  for (int i = 0; i < 8; ++i) {
    bestv[i] = 3.4e38f;
    bestc[i] = 0;
    int rl = ty * 4 + (i & 3) + ((i >> 2) * 64);
    myze2[i] = ze2[rows_l[rl]];
  }

  float acc[8][8];
#pragma unroll
  for (int i = 0; i < 8; ++i)
#pragma unroll
    for (int j = 0; j < 8; ++j) acc[i][j] = 0.0f;

  for (int kc = 0; kc < 16; ++kc) {
    int k0 = kc << 4;
    __syncthreads();
#pragma unroll
    for (int it = 0; it < 2; ++it) {
      int id = t + it * 256;
      int r = id >> 2;
      int kq = (id & 3) * 4;
      float4 v = *(const float4*)&z_e[(long)rows_l[r] * 256 + k0 + kq];
      As[kq + 0][r] = v.x; As[kq + 1][r] = v.y;
      As[kq + 2][r] = v.z; As[kq + 3][r] = v.w;
      float4 w = *(const float4*)&cbn[(long)(c0 + r) * 256 + k0 + kq];
      Ws[kq + 0][r] = w.x; Ws[kq + 1][r] = w.y;
      Ws[kq + 2][r] = w.z; Ws[kq + 3][r] = w.w;
    }
    __syncthreads();
#pragma unroll
    for (int k = 0; k < 16; ++k) {
      float av[8], bv[8];
      *(float4*)&av[0] = *(const float4*)&As[k][ty * 4];
      *(float4*)&av[4] = *(const float4*)&As[k][ty * 4 + 64];
      *(float4*)&bv[0] = *(const float4*)&Ws[k][tx * 4];
      *(float4*)&bv[4] = *(const float4*)&Ws[k][tx * 4 + 64];
#pragma unroll
      for (int i = 0; i < 8; ++i)
#pragma unroll
        for (int j = 0; j < 8; ++j)
          acc[i][j] = fmaf(av[i], bv[j], acc[i][j]);
    }
  }

  float cb2v[8];
  *(float4*)&cb2v[0] = *(const float4*)&cb2[c0 + tx * 4];
  *(float4*)&cb2v[4] = *(const float4*)&cb2[c0 + tx * 4 + 64];
#pragma unroll
  for (int i = 0; i < 8; ++i)
#pragma unroll
    for (int j = 0; j < 8; ++j) {
      int c = c0 + tx * 4 + (j & 3) + ((j >> 2) * 64);
      float d = (myze2[i] - 2.0f * acc[i][j]) + cb2v[j];
      if (d < bestv[i] || (d == bestv[i] && c < bestc[i])) {
        bestv[i] = d;
        bestc[i] = c;
      }
    }

  __syncthreads();
#pragma unroll
  for (int i = 0; i < 8; ++i) {
    int rl = ty * 4 + (i & 3) + ((i >> 2) * 64);
    rv[rl][tx] = bestv[i];
    rc[rl][tx] = bestc[i];
  }
  __syncthreads();
  if (t < 128 && r0 + t < cnt) {
    float bv = rv[t][0];
    int bc = rc[t][0];
    for (int j = 1; j < 16; ++j) {
      float v = rv[t][j];
      int c = rc[t][j];
      if (v < bv || (v == bv && c < bc)) { bv = v; bc = c; }
    }
    fixbv[(long)(r0 + t) * 8 + ctile] = bv;
    fixbc[(long)(r0 + t) * 8 + ctile] = bc;
  }
}

__global__ __launch_bounds__(256) void fixup_reduce(
    const float* __restrict__ fixbv, const int* __restrict__ fixbc,
    const int* __restrict__ fixlist, const int* __restrict__ fixcnt,
    int* __restrict__ idxc) {
  int cnt = *fixcnt;
  int i = blockIdx.x * 256 + threadIdx.x;
  if (i >= cnt) return;
  float bv = fixbv[(long)i * 8];
  int bc = fixbc[(long)i * 8];
#pragma unroll
  for (int j = 1; j < 8; ++j) {
    float v = fixbv[(long)i * 8 + j];
    int c = fixbc[(long)i * 8 + j];
    if (v < bv || (v == bv && c < bc)) { bv = v; bc = c; }
  }
  idxc[fixlist[i]] = bc;
}

// ---------------- row L2 normalize -> fp32 + sumsq (codebook prep) --------
__global__ __launch_bounds__(256) void rownorm_kernel(
    const float* __restrict__ in, float* __restrict__ outv,
    float* __restrict__ outsq) {
  int wid = threadIdx.x >> 6, lane = threadIdx.x & 63;
  long row = (long)blockIdx.x * 4 + wid;
  const float* src = in + row * 256;
  float4 v = *(const float4*)&src[lane * 4];
  float s = v.x * v.x + v.y * v.y + v.z * v.z + v.w * v.w;
#pragma unroll
  for (int off = 32; off >= 1; off >>= 1) s += __shfl_xor(s, off);
  float denom = sqrtf(s) + 1e-8f;
  float4 o;
  o.x = v.x / denom; o.y = v.y / denom; o.z = v.z / denom; o.w = v.w / denom;
  *(float4*)&outv[row * 256 + lane * 4] = o;
  float s2 = o.x * o.x + o.y * o.y + o.z * o.z + o.w * o.w;
#pragma unroll
  for (int off = 32; off >= 1; off >>= 1) s2 += __shfl_xor(s2, off);
  if (lane == 0) outsq[row] = s2;
}

// ---------------- decoder last layer on codebook table: T2 = T1 @ W2 + b2 ----
__global__ __launch_bounds__(256) void t2_kernel(
    const float* __restrict__ T1, const float* __restrict__ W,
    const float* __restrict__ bias, float* __restrict__ T2) {
  int id = blockIdx.x * 256 + threadIdx.x;
  int row = id >> 5, col = id & 31;
  const float* a = T1 + (long)row * 512;
  float s = 0.f;
#pragma unroll 8
  for (int k = 0; k < 512; ++k) s = fmaf(a[k], W[k * 32 + col], s);
  T2[id] = s + bias[col];
}

// ---------------- fused tail: ahat = T2[idx] gather, recon+commit losses ----
__global__ __launch_bounds__(256) void fused_tail(
    const float* __restrict__ z_e, const float* __restrict__ cbn,
    const int* __restrict__ idxc, const float* __restrict__ T2,
    const float* __restrict__ action, const float* __restrict__ dimw,
    float* __restrict__ partRe, float* __restrict__ partCo,
    float* __restrict__ outIdx, float* __restrict__ ahat, int pb) {
  int t = threadIdx.x, wid = t >> 6, lane = t & 63;
  float cs = 0.f, rsum = 0.f;
#pragma unroll
  for (int r = 0; r < 4; ++r) {
    long row = (long)blockIdx.x * 16 + wid * 4 + r;
    int k = idxc[row];
    float4 a = *(const float4*)&z_e[row * 256 + lane * 4];
    float4 b = *(const float4*)&cbn[(long)k * 256 + lane * 4];
    float dx = a.x - b.x, dy = a.y - b.y, dz = a.z - b.z, dq = a.w - b.w;
    cs += dx * dx + dy * dy + dz * dz + dq * dq;
    if (lane < 8) {
      float4 av = *(const float4*)&action[row * 32 + lane * 4];
      float4 tv = *(const float4*)&T2[(long)k * 32 + lane * 4];
      float4 wv = *(const float4*)&dimw[lane * 4];
      *(float4*)&ahat[row * 32 + lane * 4] = tv;
      float ex = av.x - tv.x, ey = av.y - tv.y;
      float ez = av.z - tv.z, ew = av.w - tv.w;
      rsum += ex * ex * wv.x + ey * ey * wv.y + ez * ez * wv.z + ew * ew * wv.w;
    }
    if (lane == 0) outIdx[row] = (float)k;
  }
#pragma unroll
  for (int off = 32; off >= 1; off >>= 1) {
    cs += __shfl_xor(cs, off);
    rsum += __shfl_xor(rsum, off);
  }
  __shared__ float rc[4], rr[4];
  if (lane == 0) { rc[wid] = cs; rr[wid] = rsum; }
  __syncthreads();
  if (t == 0) {
    partCo[pb + blockIdx.x] = rc[0] + rc[1] + rc[2] + rc[3];
    partRe[pb + blockIdx.x] = rr[0] + rr[1] + rr[2] + rr[3];
  }
}

__global__ void zero_kernel(int* __restrict__ cnts) {
  if (threadIdx.x < 32) cnts[threadIdx.x] = 0;
}

__global__ __launch_bounds__(256) void finalize_kernel(
    const float* __restrict__ partRe, const float* __restrict__ partCo,
    float* __restrict__ out) {
  int t = threadIdx.x;
  float sr = 0.f, sc = 0.f;
  for (int i = t; i < 4096; i += 256) { sr += partRe[i]; sc += partCo[i]; }
#pragma unroll
  for (int off = 32; off >= 1; off >>= 1) {
    sr += __shfl_xor(sr, off);
    sc += __shfl_xor(sc, off);
  }
  __shared__ float rs_[4], cs_[4];
  int wid = t >> 6, lane = t & 63;
  if (lane == 0) { rs_[wid] = sr; cs_[wid] = sc; }
  __syncthreads();
  if (t == 0) {
    float r = rs_[0] + rs_[1] + rs_[2] + rs_[3];
    float c = cs_[0] + cs_[1] + cs_[2] + cs_[3];
    out[0] = r / (65536.0f * 32.0f);
    float cl = c / (65536.0f * 256.0f);
    out[1] = cl;
    out[2] = cl;
  }
}

extern "C" void kernel_launch(void* const* d_in, const int* in_sizes, int n_in,
                              void* d_out, int out_size, void* d_ws,
                              size_t ws_size, hipStream_t stream) {
  const float* action = (const float*)d_in[0];
  const float* dimw = (const float*)d_in[1];
  const float* ew0 = (const float*)d_in[2];
  const float* eb0 = (const float*)d_in[3];
  const float* ew1 = (const float*)d_in[4];
  const float* eb1 = (const float*)d_in[5];
  const float* ew2 = (const float*)d_in[6];
  const float* eb2 = (const float*)d_in[7];
  const float* dw0 = (const float*)d_in[8];
  const float* db0 = (const float*)d_in[9];
  const float* dw1 = (const float*)d_in[10];
  const float* db1 = (const float*)d_in[11];
  const float* dw2 = (const float*)d_in[12];
  const float* db2 = (const float*)d_in[13];
  const float* cb = (const float*)d_in[14];
  float* out = (float*)d_out;
  char* ws = (char*)d_ws;

  const size_t fixed_b = 1048576 + 4096 + 1048576 + 3145728 + 1572864 +
                         4194304 + 2097152 + 131072 + 256 + 32768;
  // per-row: P0 3072 (e0 planes / z_e) + P1 4096 (e1) + 76 misc
  int R = N_ROWS;
  while (R > 2048) {
    if (fixed_b + (size_t)R * 7244 + 65536 <= ws_size) break;
    R >>= 1;
  }

  size_t off = 0;
  float* cbn = (float*)(ws + off); off += 1048576;
  float* cb2 = (float*)(ws + off); off += 4096;
  unsigned short* cbf = (unsigned short*)(ws + off); off += 1048576;
  unsigned short* ewf1 = (unsigned short*)(ws + off); off += 3145728;
  unsigned short* ewf2 = (unsigned short*)(ws + off); off += 1572864;
  float* T0 = (float*)(ws + off); off += 4194304;
  float* T1d = (float*)(ws + off); off += 2097152;
  float* T2d = (float*)(ws + off); off += 131072;
  int* fixcnts = (int*)(ws + off); off += 256;
  float* partRe = (float*)(ws + off); off += 16384;
  float* partCo = (float*)(ws + off); off += 16384;
  float* ze2 = (float*)(ws + off); off += (size_t)R * 4;
  int* idxc = (int*)(ws + off); off += (size_t)R * 4;
  int* fixlist = (int*)(ws + off); off += (size_t)R * 4;
  float* fixbv = (float*)(ws + off); off += (size_t)R * 32;
  int* fixbc = (int*)(ws + off); off += (size_t)R * 32;
  char* P0 = ws + off; off += (size_t)R * 3072;
  char* P1 = ws + off; off += (size_t)R * 4096;

  unsigned short* e0p = (unsigned short*)P0;  // 3 planes, stride R*512 shorts
  size_t aps0 = (size_t)R * 512;
  float* e1 = (float*)P1;                     // R x 1024 f32
  float* z_e = (float*)P0;                    // aliases e0p (dead after enc1)

  zero_kernel<<<1, 64, 0, stream>>>(fixcnts);
  rownorm_kernel<<<256, 256, 0, stream>>>(cb, cbn, cb2);
  frag_pack2_t<<<dim3(64, 8), 64, 0, stream>>>(cbn, cbf);
  frag_pack_kernel<<<dim3(64, 16), 64, 0, stream>>>(ew1, ewf1, 512, 1024);
  frag_pack_kernel<<<dim3(16, 32), 64, 0, stream>>>(ew2, ewf2, 1024, 256);

  // decoder table precompute: T2[k] = dec(cbn[k]) (fp32)
  gemm64_kernel<true><<<dim3(16, 16), 256, 0, stream>>>(cbn, dw0, db0, T0, 256, 1024);
  gemm64_kernel<true><<<dim3(8, 16), 256, 0, stream>>>(T0, dw1, db1, T1d, 1024, 512);
  t2_kernel<<<128, 256, 0, stream>>>(T1d, dw2, db2, T2d);

  for (int base = 0; base < N_ROWS; base += R) {
    int ci = base / R;
    const float* act_c = action + (size_t)base * 32;
    float* out_c = out + (size_t)base * 32;
    int* fixcnt = &fixcnts[ci];

    // enc0 -> pre-split 3-plane e0; enc1 MFMA (dbuf+early-issue); enc2+norm
    gemm_enc0_split<<<dim3(4, R / 128), 256, 0, stream>>>(
        act_c, ew0, eb0, e0p, aps0, 32, 512);
    mfma3_gemm<true><<<dim3(8, R / 128), 256, 0, stream>>>(
        e0p, aps0, ewf1, eb1, e1, 512, 1024);
    mfma3_norm<<<R / 64, 256, 0, stream>>>(e1, ewf2, eb2, z_e, ze2);

    dist2_mfma<<<R / 64, 256, 0, stream>>>(z_e, cbf, idxc, fixcnt, fixlist);
    fixup_part<<<dim3(8, R / 128), 256, 0, stream>>>(
        z_e, cbn, ze2, cb2, fixlist, fixcnt, fixbv, fixbc);
    fixup_reduce<<<R / 256, 256, 0, stream>>>(fixbv, fixbc, fixlist, fixcnt,
                                              idxc);

    fused_tail<<<R / 16, 256, 0, stream>>>(
        z_e, cbn, idxc, T2d, act_c, dimw, partRe, partCo,
        out + 2097152 + base, out_c, base >> 4);
  }

  finalize_kernel<<<1, 256, 0, stream>>>(partRe, partCo, out + 2162688);
}

// Round 12
// 1080.200 us; speedup vs baseline: 1.0425x; 1.0425x over previous
//
#include <hip/hip_runtime.h>
#include <math.h>

#define N_ROWS 65536

typedef short short8 __attribute__((ext_vector_type(8)));
typedef float f32x4 __attribute__((ext_vector_type(4)));

__device__ __forceinline__ float gelu_f(float x) {
  float x3 = x * x * x;
  float t = tanhf(0.7978845608028654f * (x + 0.044715f * x3));
  return 0.5f * x * (1.0f + t);
}

__device__ __forceinline__ unsigned short f2bf(float f) {
  unsigned u = __float_as_uint(f);
  unsigned r = u + 0x7fffu + ((u >> 16) & 1u);
  return (unsigned short)(r >> 16);
}
__device__ __forceinline__ float bf2f(unsigned short h) {
  return __uint_as_float(((unsigned)h) << 16);
}

// RNE split (one-time weight prep)
__device__ __forceinline__ void split3(float v, unsigned short& p0,
                                       unsigned short& p1, unsigned short& p2) {
  p0 = f2bf(v);
  float r = v - bf2f(p0);
  p1 = f2bf(r);
  r -= bf2f(p1);
  p2 = f2bf(r);
}

// cheap split: round-half-up planes 0/1 (<=0.5 ulp, exact residuals), RNE last
__device__ __forceinline__ void split3f(float v, unsigned short& p0,
                                        unsigned short& p1, unsigned short& p2) {
  unsigned u = __float_as_uint(v);
  unsigned h0 = (u + 0x8000u) & 0xffff0000u;
  float r = v - __uint_as_float(h0);
  unsigned u1 = __float_as_uint(r);
  unsigned h1 = (u1 + 0x8000u) & 0xffff0000u;
  float r2 = r - __uint_as_float(h1);
  p0 = (unsigned short)(h0 >> 16);
  p1 = (unsigned short)(h1 >> 16);
  p2 = f2bf(r2);
}

// 2-plane split: residual after 2 planes <= 2^-17 * |v|
__device__ __forceinline__ void split2f(float v, unsigned short& p0,
                                        unsigned short& p1) {
  unsigned u = __float_as_uint(v);
  unsigned h0 = (u + 0x8000u) & 0xffff0000u;
  float r = v - __uint_as_float(h0);
  p0 = (unsigned short)(h0 >> 16);
  p1 = f2bf(r);
}

__device__ __forceinline__ f32x4 mfma16(short8 a, short8 b, f32x4 c) {
  return __builtin_amdgcn_mfma_f32_16x16x32_bf16(a, b, c, 0, 0, 0);
}

// ---------------- enc0: P_planes = split3(gelu(A @ W + b)) ----------------
__global__ __launch_bounds__(256) void gemm_enc0_split(
    const float* __restrict__ A, const float* __restrict__ W,
    const float* __restrict__ bias, unsigned short* __restrict__ P,
    size_t aps, int din, int dout) {
  __shared__ float As[16][132];
  __shared__ float Ws[16][132];
  int t = threadIdx.x;
  int tx = t & 15, ty = t >> 4;
  int c0 = blockIdx.x * 128;
  int r0 = blockIdx.y * 128;

  float acc[8][8];
#pragma unroll
  for (int i = 0; i < 8; ++i)
#pragma unroll
    for (int j = 0; j < 8; ++j) acc[i][j] = 0.0f;

  int kchunks = din >> 4;
  for (int kc = 0; kc < kchunks; ++kc) {
    int k0 = kc << 4;
    __syncthreads();
#pragma unroll
    for (int it = 0; it < 2; ++it) {
      int id = t + it * 256;
      int r = id >> 2;
      int kq = (id & 3) * 4;
      float4 v = *(const float4*)&A[(long)(r0 + r) * din + (k0 + kq)];
      As[kq + 0][r] = v.x; As[kq + 1][r] = v.y;
      As[kq + 2][r] = v.z; As[kq + 3][r] = v.w;
      int k = id >> 5;
      int cq = (id & 31) * 4;
      float4 w = *(const float4*)&W[(long)(k0 + k) * dout + (c0 + cq)];
      *(float4*)&Ws[k][cq] = w;
    }
    __syncthreads();
#pragma unroll
    for (int k = 0; k < 16; ++k) {
      float av[8], bv[8];
      *(float4*)&av[0] = *(const float4*)&As[k][ty * 4];
      *(float4*)&av[4] = *(const float4*)&As[k][ty * 4 + 64];
      *(float4*)&bv[0] = *(const float4*)&Ws[k][tx * 4];
      *(float4*)&bv[4] = *(const float4*)&Ws[k][tx * 4 + 64];
#pragma unroll
      for (int i = 0; i < 8; ++i)
#pragma unroll
        for (int j = 0; j < 8; ++j)
          acc[i][j] = fmaf(av[i], bv[j], acc[i][j]);
    }
  }

  float bbv[8];
  *(float4*)&bbv[0] = *(const float4*)&bias[c0 + tx * 4];
  *(float4*)&bbv[4] = *(const float4*)&bias[c0 + tx * 4 + 64];
#pragma unroll
  for (int i = 0; i < 8; ++i) {
    long row = r0 + ty * 4 + (i & 3) + ((i >> 2) * 64);
    unsigned short s0[8], s1[8], s2[8];
#pragma unroll
    for (int j = 0; j < 8; ++j) {
      float v = gelu_f(acc[i][j] + bbv[j]);
      split3f(v, s0[j], s1[j], s2[j]);
    }
    size_t b = (size_t)row * dout + c0 + tx * 4;
    ushort4 w;
    w.x = s0[0]; w.y = s0[1]; w.z = s0[2]; w.w = s0[3];
    *(ushort4*)&P[b] = w;
    w.x = s0[4]; w.y = s0[5]; w.z = s0[6]; w.w = s0[7];
    *(ushort4*)&P[b + 64] = w;
    w.x = s1[0]; w.y = s1[1]; w.z = s1[2]; w.w = s1[3];
    *(ushort4*)&P[aps + b] = w;
    w.x = s1[4]; w.y = s1[5]; w.z = s1[6]; w.w = s1[7];
    *(ushort4*)&P[aps + b + 64] = w;
    w.x = s2[0]; w.y = s2[1]; w.z = s2[2]; w.w = s2[3];
    *(ushort4*)&P[2 * aps + b] = w;
    w.x = s2[4]; w.y = s2[5]; w.z = s2[6]; w.w = s2[7];
    *(ushort4*)&P[2 * aps + b + 64] = w;
  }
}

// ---------------- fp32 GEMM 64x64 (small-M precompute) ----------------
template <bool GELU>
__global__ __launch_bounds__(256) void gemm64_kernel(
    const float* __restrict__ A, const float* __restrict__ W,
    const float* __restrict__ bias, float* __restrict__ C,
    int din, int dout) {
  __shared__ float As[16][68];
  __shared__ float Ws[16][68];
  int t = threadIdx.x;
  int tx = t & 15, ty = t >> 4;
  int c0 = blockIdx.x * 64;
  int r0 = blockIdx.y * 64;

  float acc[4][4];
#pragma unroll
  for (int i = 0; i < 4; ++i)
#pragma unroll
    for (int j = 0; j < 4; ++j) acc[i][j] = 0.0f;

  int kchunks = din >> 4;
  for (int kc = 0; kc < kchunks; ++kc) {
    int k0 = kc << 4;
    __syncthreads();
    {
      int r = t >> 2, kq = (t & 3) * 4;
      float4 v = *(const float4*)&A[(long)(r0 + r) * din + (k0 + kq)];
      As[kq + 0][r] = v.x; As[kq + 1][r] = v.y;
      As[kq + 2][r] = v.z; As[kq + 3][r] = v.w;
      int k = t >> 4, cq = (t & 15) * 4;
      *(float4*)&Ws[k][cq] = *(const float4*)&W[(long)(k0 + k) * dout + (c0 + cq)];
    }
    __syncthreads();
#pragma unroll
    for (int k = 0; k < 16; ++k) {
      float av[4], bv[4];
      *(float4*)&av[0] = *(const float4*)&As[k][ty * 4];
      *(float4*)&bv[0] = *(const float4*)&Ws[k][tx * 4];
#pragma unroll
      for (int i = 0; i < 4; ++i)
#pragma unroll
        for (int j = 0; j < 4; ++j)
          acc[i][j] = fmaf(av[i], bv[j], acc[i][j]);
    }
  }

  float4 bb = *(const float4*)&bias[c0 + tx * 4];
#pragma unroll
  for (int i = 0; i < 4; ++i) {
    long row = r0 + ty * 4 + i;
    float o[4];
    o[0] = acc[i][0] + bb.x; o[1] = acc[i][1] + bb.y;
    o[2] = acc[i][2] + bb.z; o[3] = acc[i][3] + bb.w;
    if (GELU) {
      o[0] = gelu_f(o[0]); o[1] = gelu_f(o[1]);
      o[2] = gelu_f(o[2]); o[3] = gelu_f(o[3]);
    }
    *(float4*)&C[row * dout + c0 + tx * 4] = *(float4*)&o[0];
  }
}

// ---- W [K][N] fp32 -> 3-plane MFMA-fragment-major Bfrag ----
__global__ void frag_pack_kernel(const float* __restrict__ W,
                                 unsigned short* __restrict__ Bf,
                                 int K, int N) {
  int l = threadIdx.x;
  int m = l & 15, q = l >> 4;
  int cb = blockIdx.x, kb = blockIdx.y;
  unsigned short s0[8], s1[8], s2[8];
#pragma unroll
  for (int j = 0; j < 8; ++j) {
    float v = W[(long)(kb * 32 + q * 8 + j) * N + cb * 16 + m];
    split3(v, s0[j], s1[j], s2[j]);
  }
  size_t base = ((size_t)cb * (K / 32) + kb) * 3 * 512;
  *(short8*)&Bf[base + 0 * 512 + l * 8] = *(short8*)s0;
  *(short8*)&Bf[base + 1 * 512 + l * 8] = *(short8*)s1;
  *(short8*)&Bf[base + 2 * 512 + l * 8] = *(short8*)s2;
}

// ---- cbn [1024][256] fp32 -> 2-plane fragment-major (B = cbn^T) ----
__global__ void frag_pack2_t(const float* __restrict__ cbn,
                             unsigned short* __restrict__ Bf) {
  int l = threadIdx.x;
  int m = l & 15, q = l >> 4;
  int cb = blockIdx.x, kb = blockIdx.y;
  unsigned short s0[8], s1[8];
  const float* src = cbn + (long)(cb * 16 + m) * 256 + kb * 32 + q * 8;
#pragma unroll
  for (int j = 0; j < 8; ++j) split2f(src[j], s0[j], s1[j]);
  size_t base = ((size_t)(cb * 8 + kb) * 2) * 512;
  *(short8*)&Bf[base + l * 8] = *(short8*)s0;
  *(short8*)&Bf[base + 512 + l * 8] = *(short8*)s1;
}

// ---------------- bf16x3-split MFMA GEMM, double-buffered LDS (R6) --------
template <bool GELU>
__global__ __launch_bounds__(256) void mfma3_gemm(
    const unsigned short* __restrict__ Ap, size_t aps,
    const unsigned short* __restrict__ Bf,
    const float* __restrict__ bias, float* __restrict__ C,
    int K, int dout) {
  // 2 x [p 3][wrb 2][x 4][granule 64][8 shorts] = 49152 B
  __shared__ unsigned short A_f[2][3 * 2 * 4 * 512];
  int t = threadIdx.x;
  int lane = t & 63, wave = t >> 6;
  int q = lane >> 4, m = lane & 15;
  int wrb = wave >> 1;
  int wr = wrb * 64, wc = (wave & 1) * 64;

  // XCD-aware remap: contiguous row-panel runs per XCD (L2 locality).
  int gx = gridDim.x, tot = gx * gridDim.y;
  int lin = blockIdx.y * gx + blockIdx.x;
  if (!(tot & 7)) lin = (lin & 7) * (tot >> 3) + (lin >> 3);
  int bx = lin % gx, by = lin / gx;

  long r0 = (long)by * 128;
  int c0 = bx * 128;
  int kchunks = K >> 5;

  f32x4 acc[4][4];
#pragma unroll
  for (int i = 0; i < 4; ++i)
#pragma unroll
    for (int j = 0; j < 4; ++j) acc[i][j] = (f32x4){0.f, 0.f, 0.f, 0.f};

  int rs = t >> 1, hs = (t & 1) * 16;
  const unsigned short* a0p = Ap + (size_t)(r0 + rs) * K + hs;
  const unsigned short* a1p = a0p + aps;
  const unsigned short* a2p = a0p + 2 * aps;
  int cb0 = (c0 + wc) >> 4;
  // writer-side fragment coordinates
  int xw = (rs >> 4) & 3, wrbw = rs >> 6, mw = rs & 15;
  int g0 = ((t & 1) * 2 + 0) * 16 + mw;
  int g1 = ((t & 1) * 2 + 1) * 16 + mw;
  int wb0 = (0 * 2 + wrbw) * 4 + xw;
  int wb1 = (1 * 2 + wrbw) * 4 + xw;
  int wb2 = (2 * 2 + wrbw) * 4 + xw;

  // prologue: stage tile 0 into buffer 0
  {
    uint4 u00 = *(const uint4*)(a0p);
    uint4 u01 = *(const uint4*)(a0p + 8);
    uint4 u10 = *(const uint4*)(a1p);
    uint4 u11 = *(const uint4*)(a1p + 8);
    uint4 u20 = *(const uint4*)(a2p);
    uint4 u21 = *(const uint4*)(a2p + 8);
    *(uint4*)&A_f[0][wb0 * 512 + g0 * 8] = u00;
    *(uint4*)&A_f[0][wb0 * 512 + g1 * 8] = u01;
    *(uint4*)&A_f[0][wb1 * 512 + g0 * 8] = u10;
    *(uint4*)&A_f[0][wb1 * 512 + g1 * 8] = u11;
    *(uint4*)&A_f[0][wb2 * 512 + g0 * 8] = u20;
    *(uint4*)&A_f[0][wb2 * 512 + g1 * 8] = u21;
  }
  __syncthreads();

  int cur = 0;
  for (int kb = 0; kb < kchunks; ++kb) {
    // compute from A_f[cur] (per-ct B loads interleave w/ MFMA)
    short8 af[3][4];
#pragma unroll
    for (int p = 0; p < 3; ++p)
#pragma unroll
      for (int x = 0; x < 4; ++x)
        af[p][x] =
            *(const short8*)&A_f[cur][((p * 2 + wrb) * 4 + x) * 512 + lane * 8];
#pragma unroll
    for (int ct = 0; ct < 4; ++ct) {
      size_t fb = ((size_t)(cb0 + ct) * kchunks + kb) * 3 * 512 + lane * 8;
      short8 b0 = *(const short8*)&Bf[fb];
      short8 b1 = *(const short8*)&Bf[fb + 512];
      short8 b2 = *(const short8*)&Bf[fb + 1024];
#pragma unroll
      for (int rt = 0; rt < 4; ++rt) {
        acc[rt][ct] = mfma16(af[0][rt], b0, acc[rt][ct]);
        acc[rt][ct] = mfma16(af[0][rt], b1, acc[rt][ct]);
        acc[rt][ct] = mfma16(af[1][rt], b0, acc[rt][ct]);
        acc[rt][ct] = mfma16(af[0][rt], b2, acc[rt][ct]);
        acc[rt][ct] = mfma16(af[1][rt], b1, acc[rt][ct]);
        acc[rt][ct] = mfma16(af[2][rt], b0, acc[rt][ct]);
      }
    }
    // stage tile kb+1 into the other buffer (overlaps other waves' compute)
    if (kb + 1 < kchunks) {
      int kt = (kb + 1) << 5;
      uint4 u00 = *(const uint4*)(a0p + kt);
      uint4 u01 = *(const uint4*)(a0p + kt + 8);
      uint4 u10 = *(const uint4*)(a1p + kt);
      uint4 u11 = *(const uint4*)(a1p + kt + 8);
      uint4 u20 = *(const uint4*)(a2p + kt);
      uint4 u21 = *(const uint4*)(a2p + kt + 8);
      int nb = cur ^ 1;
      *(uint4*)&A_f[nb][wb0 * 512 + g0 * 8] = u00;
      *(uint4*)&A_f[nb][wb0 * 512 + g1 * 8] = u01;
      *(uint4*)&A_f[nb][wb1 * 512 + g0 * 8] = u10;
      *(uint4*)&A_f[nb][wb1 * 512 + g1 * 8] = u11;
      *(uint4*)&A_f[nb][wb2 * 512 + g0 * 8] = u20;
      *(uint4*)&A_f[nb][wb2 * 512 + g1 * 8] = u21;
    }
    __syncthreads();
    cur ^= 1;
  }

#pragma unroll
  for (int ct = 0; ct < 4; ++ct) {
    long col = c0 + wc + ct * 16 + m;
    float bv = bias[col];
#pragma unroll
    for (int rt = 0; rt < 4; ++rt) {
      long rowb = r0 + wr + rt * 16 + q * 4;
#pragma unroll
      for (int r = 0; r < 4; ++r) {
        float v = acc[rt][ct][r] + bv;
        if (GELU) v = gelu_f(v);
        C[(rowb + r) * dout + col] = v;
      }
    }
  }
}

// ---------------- enc2 + rownorm fused, double-buffered LDS (R6) ----------
__global__ __launch_bounds__(256) void mfma3_norm(
    const float* __restrict__ A, const unsigned short* __restrict__ Bf,
    const float* __restrict__ bias, float* __restrict__ z_e,
    float* __restrict__ ze2) {
  __shared__ unsigned short A_f[2][3 * 4 * 512];  // 2 x 12 KB
  __shared__ float S[64][4];
  __shared__ float Sinv[64];
  const int K = 1024, kchunks = 32;
  int t = threadIdx.x;
  int lane = t & 63, wave = t >> 6;  // wave = col quarter
  int q = lane >> 4, m = lane & 15;
  long r0 = (long)blockIdx.x * 64;

  f32x4 acc[4][4];
#pragma unroll
  for (int i = 0; i < 4; ++i)
#pragma unroll
    for (int j = 0; j < 4; ++j) acc[i][j] = (f32x4){0.f, 0.f, 0.f, 0.f};

  int rs = t >> 2, kq = t & 3;
  const float* aptr = A + (r0 + rs) * K + kq * 8;
  int xw = rs >> 4, mw = rs & 15;
  int gw = kq * 16 + mw;
  int wb0 = 0 * 4 + xw, wb1 = 1 * 4 + xw, wb2 = 2 * 4 + xw;
  int cb0 = wave * 4;

  // prologue: stage k-tile 0 into buffer 0
  {
    float fv[8];
    *(float4*)&fv[0] = *(const float4*)(aptr);
    *(float4*)&fv[4] = *(const float4*)(aptr + 4);
    unsigned short a0[8], a1[8], a2[8];
#pragma unroll
    for (int i = 0; i < 8; ++i) split3f(fv[i], a0[i], a1[i], a2[i]);
    *(uint4*)&A_f[0][wb0 * 512 + gw * 8] = *(uint4*)a0;
    *(uint4*)&A_f[0][wb1 * 512 + gw * 8] = *(uint4*)a1;
    *(uint4*)&A_f[0][wb2 * 512 + gw * 8] = *(uint4*)a2;
  }
  __syncthreads();

  int cur = 0;
  for (int kb = 0; kb < kchunks; ++kb) {
    short8 af[3][4];
#pragma unroll
    for (int p = 0; p < 3; ++p)
#pragma unroll
      for (int x = 0; x < 4; ++x)
        af[p][x] = *(const short8*)&A_f[cur][(p * 4 + x) * 512 + lane * 8];
#pragma unroll
    for (int ct = 0; ct < 4; ++ct) {
      size_t fb = ((size_t)(cb0 + ct) * kchunks + kb) * 3 * 512 + lane * 8;
      short8 b0 = *(const short8*)&Bf[fb];
      short8 b1 = *(const short8*)&Bf[fb + 512];
      short8 b2 = *(const short8*)&Bf[fb + 1024];
#pragma unroll
      for (int rt = 0; rt < 4; ++rt) {
        acc[rt][ct] = mfma16(af[0][rt], b0, acc[rt][ct]);
        acc[rt][ct] = mfma16(af[0][rt], b1, acc[rt][ct]);
        acc[rt][ct] = mfma16(af[1][rt], b0, acc[rt][ct]);
        acc[rt][ct] = mfma16(af[0][rt], b2, acc[rt][ct]);
        acc[rt][ct] = mfma16(af[1][rt], b1, acc[rt][ct]);
        acc[rt][ct] = mfma16(af[2][rt], b0, acc[rt][ct]);
      }
    }
    if (kb + 1 < kchunks) {
      float fv[8];
      *(float4*)&fv[0] = *(const float4*)(aptr + ((kb + 1) << 5));
      *(float4*)&fv[4] = *(const float4*)(aptr + ((kb + 1) << 5) + 4);
      unsigned short a0[8], a1[8], a2[8];
#pragma unroll
      for (int i = 0; i < 8; ++i) split3f(fv[i], a0[i], a1[i], a2[i]);
      int nb = cur ^ 1;
      *(uint4*)&A_f[nb][wb0 * 512 + gw * 8] = *(uint4*)a0;
      *(uint4*)&A_f[nb][wb1 * 512 + gw * 8] = *(uint4*)a1;
      *(uint4*)&A_f[nb][wb2 * 512 + gw * 8] = *(uint4*)a2;
    }
    __syncthreads();
    cur ^= 1;
  }

  // bias add (no gelu on last encoder layer)
#pragma unroll
  for (int ct = 0; ct < 4; ++ct) {
    float bv = bias[wave * 64 + ct * 16 + m];
#pragma unroll
    for (int rt = 0; rt < 4; ++rt)
#pragma unroll
      for (int r = 0; r < 4; ++r) acc[rt][ct][r] += bv;
  }

  // per-row sumsq partial over this wave's 64 cols
#pragma unroll
  for (int rt = 0; rt < 4; ++rt)
#pragma unroll
    for (int r = 0; r < 4; ++r) {
      float s = acc[rt][0][r] * acc[rt][0][r] + acc[rt][1][r] * acc[rt][1][r] +
                acc[rt][2][r] * acc[rt][2][r] + acc[rt][3][r] * acc[rt][3][r];
#pragma unroll
      for (int off = 1; off <= 8; off <<= 1) s += __shfl_xor(s, off);
      if (m == 0) S[rt * 16 + q * 4 + r][wave] = s;
    }
  __syncthreads();
  if (t < 64) {
    float s = S[t][0] + S[t][1] + S[t][2] + S[t][3];
    float den = sqrtf(s) + 1e-8f;
    Sinv[t] = 1.0f / den;
    ze2[r0 + t] = s / (den * den);
  }
  __syncthreads();
#pragma unroll
  for (int rt = 0; rt < 4; ++rt)
#pragma unroll
    for (int r = 0; r < 4; ++r) {
      int rl = rt * 16 + q * 4 + r;
      float inv = Sinv[rl];
#pragma unroll
      for (int ct = 0; ct < 4; ++ct)
        z_e[(r0 + rl) * 256 + wave * 64 + ct * 16 + m] = acc[rt][ct][r] * inv;
    }
}

// ---------------- 2-plane bf16-split MFMA distances: top-2 of z_e . cb^T ----
// B fragments register-double-buffered one kb ahead (R10 win).
__global__ __launch_bounds__(256) void dist2_mfma(
    const float* __restrict__ z_e, const unsigned short* __restrict__ cbf,
    int* __restrict__ idxc, int* __restrict__ fixcnt, int* __restrict__ fixlist) {
  // [p 2][kb 8][x 4][granule 64][8 shorts] = 64 KB
  __shared__ unsigned short A_f[2 * 8 * 4 * 512];
  __shared__ float Lv1[64][4], Lv2[64][4];
  __shared__ int Lc1[64][4];
  int t = threadIdx.x;
  int lane = t & 63, wave = t >> 6;
  int q = lane >> 4, m = lane & 15;
  long r0 = (long)blockIdx.x * 64;

#pragma unroll
  for (int it = 0; it < 4; ++it) {
    int kb = it * 2 + (t >> 7);
    int rs = (t & 127) >> 1, hs = (t & 1) * 16;
    const float* ap = z_e + (r0 + rs) * 256 + kb * 32 + hs;
    float fv[16];
    *(float4*)&fv[0] = *(const float4*)(ap + 0);
    *(float4*)&fv[4] = *(const float4*)(ap + 4);
    *(float4*)&fv[8] = *(const float4*)(ap + 8);
    *(float4*)&fv[12] = *(const float4*)(ap + 12);
    unsigned short a0[16], a1[16];
#pragma unroll
    for (int i = 0; i < 16; ++i) split2f(fv[i], a0[i], a1[i]);
    int x = rs >> 4, mm = rs & 15;
    int ga = ((t & 1) * 2 + 0) * 16 + mm;
    int gb = ((t & 1) * 2 + 1) * 16 + mm;
    int b0 = ((0 * 8 + kb) * 4 + x) * 512;
    int b1 = ((1 * 8 + kb) * 4 + x) * 512;
    *(uint4*)&A_f[b0 + ga * 8] = ((uint4*)a0)[0];
    *(uint4*)&A_f[b0 + gb * 8] = ((uint4*)a0)[1];
    *(uint4*)&A_f[b1 + ga * 8] = ((uint4*)a1)[0];
    *(uint4*)&A_f[b1 + gb * 8] = ((uint4*)a1)[1];
  }
  __syncthreads();

  float v1[4][4], v2[4][4];
  int c1[4][4];
#pragma unroll
  for (int i = 0; i < 4; ++i)
#pragma unroll
    for (int j = 0; j < 4; ++j) { v1[i][j] = -3.4e38f; v2[i][j] = -3.4e38f; c1[i][j] = 0; }

  // prefetch B fragments for (ctp=0, kb=0)
  short8 bf0[4], bf1[4];
#pragma unroll
  for (int cs = 0; cs < 4; ++cs) {
    int cb = 0 * 16 + (cs >> 1) * 8 + wave * 2 + (cs & 1);
    size_t fb = ((size_t)(cb * 8 + 0) * 2) * 512 + lane * 8;
    bf0[cs] = *(const short8*)&cbf[fb];
    bf1[cs] = *(const short8*)&cbf[fb + 512];
  }

  for (int ctp = 0; ctp < 4; ++ctp) {
    f32x4 acc[4][4];
#pragma unroll
    for (int i = 0; i < 4; ++i)
#pragma unroll
      for (int j = 0; j < 4; ++j) acc[i][j] = (f32x4){0.f, 0.f, 0.f, 0.f};

    for (int kb = 0; kb < 8; ++kb) {
      // issue next iteration's B loads (consumed after this MFMA block)
      short8 nb0[4], nb1[4];
      int kbn = (kb + 1) & 7;
      int ctpn = (kb == 7) ? ctp + 1 : ctp;
      if (ctpn < 4) {
#pragma unroll
        for (int cs = 0; cs < 4; ++cs) {
          int cb = ctpn * 16 + (cs >> 1) * 8 + wave * 2 + (cs & 1);
          size_t fb = ((size_t)(cb * 8 + kbn) * 2) * 512 + lane * 8;
          nb0[cs] = *(const short8*)&cbf[fb];
          nb1[cs] = *(const short8*)&cbf[fb + 512];
        }
      }
      short8 af0[4], af1[4];
#pragma unroll
      for (int rt = 0; rt < 4; ++rt) {
        af0[rt] = *(const short8*)&A_f[((0 * 8 + kb) * 4 + rt) * 512 + lane * 8];
        af1[rt] = *(const short8*)&A_f[((1 * 8 + kb) * 4 + rt) * 512 + lane * 8];
      }
#pragma unroll
      for (int rt = 0; rt < 4; ++rt)
#pragma unroll
        for (int cs = 0; cs < 4; ++cs) {
          acc[rt][cs] = mfma16(af0[rt], bf0[cs], acc[rt][cs]);
          acc[rt][cs] = mfma16(af0[rt], bf1[cs], acc[rt][cs]);
          acc[rt][cs] = mfma16(af1[rt], bf0[cs], acc[rt][cs]);
        }
      if (ctpn < 4) {
#pragma unroll
        for (int cs = 0; cs < 4; ++cs) { bf0[cs] = nb0[cs]; bf1[cs] = nb1[cs]; }
      }
    }
#pragma unroll
    for (int rt = 0; rt < 4; ++rt)
#pragma unroll
      for (int cs = 0; cs < 4; ++cs) {
        int colb = ctp * 256 + (cs >> 1) * 128 + wave * 32 + (cs & 1) * 16 + m;
#pragma unroll
        for (int r = 0; r < 4; ++r) {
          float v = acc[rt][cs][r];
          float nv2 = fmaxf(v2[rt][r], fminf(v, v1[rt][r]));
          if (v > v1[rt][r]) { c1[rt][r] = colb; v1[rt][r] = v; }
          v2[rt][r] = nv2;
        }
      }
  }

#pragma unroll
  for (int off = 1; off <= 8; off <<= 1) {
#pragma unroll
    for (int rt = 0; rt < 4; ++rt)
#pragma unroll
      for (int r = 0; r < 4; ++r) {
        float ov1 = __shfl_xor(v1[rt][r], off);
        float ov2 = __shfl_xor(v2[rt][r], off);
        int oc1 = __shfl_xor(c1[rt][r], off);
        float nv2 = fmaxf(fmaxf(v2[rt][r], ov2), fminf(v1[rt][r], ov1));
        if (ov1 > v1[rt][r] || (ov1 == v1[rt][r] && oc1 < c1[rt][r])) {
          v1[rt][r] = ov1; c1[rt][r] = oc1;
        }
        v2[rt][r] = nv2;
      }
  }
  if (m == 0) {
#pragma unroll
    for (int rt = 0; rt < 4; ++rt)
#pragma unroll
      for (int r = 0; r < 4; ++r) {
        int rloc = rt * 16 + q * 4 + r;
        Lv1[rloc][wave] = v1[rt][r];
        Lv2[rloc][wave] = v2[rt][r];
        Lc1[rloc][wave] = c1[rt][r];
      }
  }
  __syncthreads();
  if (t < 64) {
    float a1 = Lv1[t][0], a2 = Lv2[t][0];
    int ac = Lc1[t][0];
#pragma unroll
    for (int w = 1; w < 4; ++w) {
      float b1 = Lv1[t][w], b2 = Lv2[t][w];
      int bc = Lc1[t][w];
      float n2 = fmaxf(fmaxf(a2, b2), fminf(a1, b1));
      if (b1 > a1 || (b1 == a1 && bc < ac)) { a1 = b1; ac = bc; }
      a2 = n2;
    }
    idxc[r0 + t] = ac;
    if (a1 - a2 < 5.0e-4f) {
      int p = atomicAdd(fixcnt, 1);
      fixlist[p] = r0 + t;
    }
  }
}

// ---------------- fp32 exact argmin fixup, code-parallel ----------------
__global__ __launch_bounds__(256) void fixup_part(
    const float* __restrict__ z_e, const float* __restrict__ cbn,
    const float* __restrict__ ze2, const float* __restrict__ cb2,
    const int* __restrict__ fixlist, const int* __restrict__ fixcnt,
    float* __restrict__ fixbv, int* __restrict__ fixbc) {
  int cnt = *fixcnt;
  int r0 = blockIdx.y * 128;
  if (r0 >= cnt) return;
  int ctile = blockIdx.x;
  int c0 = ctile * 128;
  __shared__ float As[16][132];
  __shared__ float Ws[16][132];
  __shared__ float rv[128][17];
  __shared__ int rc[128][17];
  __shared__ int rows_l[128];
  int t = threadIdx.x, tx = t & 15, ty = t >> 4;

  if (t < 128) rows_l[t] = fixlist[(r0 + t < cnt) ? (r0 + t) : 0];
  __syncthreads();

  float bestv[8];
  int bestc[8];
  float myze2[8];
#pragma unroll
  for (int i = 0; i < 8; ++i) {
    bestv[i] = 3.4e38f;
    bestc[i] = 0;
    int rl = ty * 4 + (i & 3) + ((i >> 2) * 64);
    myze2[i] = ze2[rows_l[rl]];
  }

  float acc[8][8];
#pragma unroll
  for (int i = 0; i < 8; ++i)
#pragma unroll
    for (int j = 0; j < 8; ++j) acc[i][j] = 0.0f;

  for (int kc = 0; kc < 16; ++kc) {
    int k0 = kc << 4;
    __syncthreads();
#pragma unroll
    for (int it = 0; it < 2; ++it) {
      int id = t + it * 256;
      int r = id >> 2;
      int kq = (id & 3) * 4;
      float4 v = *(const float4*)&z_e[(long)rows_l[r] * 256 + k0 + kq];
      As[kq + 0][r] = v.x; As[kq + 1][r] = v.y;
      As[kq + 2][r] = v.z; As[kq + 3][r] = v.w;
      float4 w = *(const float4*)&cbn[(long)(c0 + r) * 256 + k0 + kq];
      Ws[kq + 0][r] = w.x; Ws[kq + 1][r] = w.y;
      Ws[kq + 2][r] = w.z; Ws[kq + 3][r] = w.w;
    }
    __syncthreads();
#pragma unroll
    for (int k = 0; k < 16; ++k) {
      float av[8], bv[8];
      *(float4*)&av[0] = *(const float4*)&As[k][ty * 4];
      *(float4*)&av[4] = *(const float4*)&As[k][ty * 4 + 64];
      *(float4*)&bv[0] = *(const float4*)&Ws[k][tx * 4];
      *(float4*)&bv[4] = *(const float4*)&Ws[k][tx * 4 + 64];
#pragma unroll
      for (int i = 0; i < 8; ++i)
#pragma unroll
        for (int j = 0; j < 8; ++j)
          acc[i][j] = fmaf(av[i], bv[j], acc[i][j]);
    }
  }

  float cb2v[8];
  *(float4*)&cb2v[0] = *(const float4*)&cb2[c0 + tx * 4];
  *(float4*)&cb2v[4] = *(const float4*)&cb2[c0 + tx * 4 + 64];
#pragma unroll
  for (int i = 0; i < 8; ++i)
#pragma unroll
    for (int j = 0; j < 8; ++j) {
      int c = c0 + tx * 4 + (j & 3) + ((j >> 2) * 64);
      float d = (myze2[i] - 2.0f * acc[i][j]) + cb2v[j];
      if (d < bestv[i] || (d == bestv[i] && c < bestc[i])) {
        bestv[i] = d;
        bestc[i] = c;
      }
    }

  __syncthreads();
#pragma unroll
  for (int i = 0; i < 8; ++i) {
    int rl = ty * 4 + (i & 3) + ((i >> 2) * 64);
    rv[rl][tx] = bestv[i];
    rc[rl][tx] = bestc[i];
  }
  __syncthreads();
  if (t < 128 && r0 + t < cnt) {
    float bv = rv[t][0];
    int bc = rc[t][0];
    for (int j = 1; j < 16; ++j) {
      float v = rv[t][j];
      int c = rc[t][j];
      if (v < bv || (v == bv && c < bc)) { bv = v; bc = c; }
    }
    fixbv[(long)(r0 + t) * 8 + ctile] = bv;
    fixbc[(long)(r0 + t) * 8 + ctile] = bc;
  }
}

__global__ __launch_bounds__(256) void fixup_reduce(
    const float* __restrict__ fixbv, const int* __restrict__ fixbc,
    const int* __restrict__ fixlist, const int* __restrict__ fixcnt,
    int* __restrict__ idxc) {
  int cnt = *fixcnt;
  int i = blockIdx.x * 256 + threadIdx.x;
  if (i >= cnt) return;
  float bv = fixbv[(long)i * 8];
  int bc = fixbc[(long)i * 8];
#pragma unroll
  for (int j = 1; j < 8; ++j) {
    float v = fixbv[(long)i * 8 + j];
    int c = fixbc[(long)i * 8 + j];
    if (v < bv || (v == bv && c < bc)) { bv = v; bc = c; }
  }
  idxc[fixlist[i]] = bc;
}

// ---------------- row L2 normalize -> fp32 + sumsq (codebook prep) --------
__global__ __launch_bounds__(256) void rownorm_kernel(
    const float* __restrict__ in, float* __restrict__ outv,
    float* __restrict__ outsq) {
  int wid = threadIdx.x >> 6, lane = threadIdx.x & 63;
  long row = (long)blockIdx.x * 4 + wid;
  const float* src = in + row * 256;
  float4 v = *(const float4*)&src[lane * 4];
  float s = v.x * v.x + v.y * v.y + v.z * v.z + v.w * v.w;
#pragma unroll
  for (int off = 32; off >= 1; off >>= 1) s += __shfl_xor(s, off);
  float denom = sqrtf(s) + 1e-8f;
  float4 o;
  o.x = v.x / denom; o.y = v.y / denom; o.z = v.z / denom; o.w = v.w / denom;
  *(float4*)&outv[row * 256 + lane * 4] = o;
  float s2 = o.x * o.x + o.y * o.y + o.z * o.z + o.w * o.w;
#pragma unroll
  for (int off = 32; off >= 1; off >>= 1) s2 += __shfl_xor(s2, off);
  if (lane == 0) outsq[row] = s2;
}

// ---------------- decoder last layer on codebook table: T2 = T1 @ W2 + b2 ----
__global__ __launch_bounds__(256) void t2_kernel(
    const float* __restrict__ T1, const float* __restrict__ W,
    const float* __restrict__ bias, float* __restrict__ T2) {
  int id = blockIdx.x * 256 + threadIdx.x;
  int row = id >> 5, col = id & 31;
  const float* a = T1 + (long)row * 512;
  float s = 0.f;
#pragma unroll 8
  for (int k = 0; k < 512; ++k) s = fmaf(a[k], W[k * 32 + col], s);
  T2[id] = s + bias[col];
}

// ---------------- fused tail: ahat = T2[idx] gather, recon+commit losses ----
__global__ __launch_bounds__(256) void fused_tail(
    const float* __restrict__ z_e, const float* __restrict__ cbn,
    const int* __restrict__ idxc, const float* __restrict__ T2,
    const float* __restrict__ action, const float* __restrict__ dimw,
    float* __restrict__ partRe, float* __restrict__ partCo,
    float* __restrict__ outIdx, float* __restrict__ ahat, int pb) {
  int t = threadIdx.x, wid = t >> 6, lane = t & 63;
  float cs = 0.f, rsum = 0.f;
#pragma unroll
  for (int r = 0; r < 4; ++r) {
    long row = (long)blockIdx.x * 16 + wid * 4 + r;
    int k = idxc[row];
    float4 a = *(const float4*)&z_e[row * 256 + lane * 4];
    float4 b = *(const float4*)&cbn[(long)k * 256 + lane * 4];
    float dx = a.x - b.x, dy = a.y - b.y, dz = a.z - b.z, dq = a.w - b.w;
    cs += dx * dx + dy * dy + dz * dz + dq * dq;
    if (lane < 8) {
      float4 av = *(const float4*)&action[row * 32 + lane * 4];
      float4 tv = *(const float4*)&T2[(long)k * 32 + lane * 4];
      float4 wv = *(const float4*)&dimw[lane * 4];
      *(float4*)&ahat[row * 32 + lane * 4] = tv;
      float ex = av.x - tv.x, ey = av.y - tv.y;
      float ez = av.z - tv.z, ew = av.w - tv.w;
      rsum += ex * ex * wv.x + ey * ey * wv.y + ez * ez * wv.z + ew * ew * wv.w;
    }
    if (lane == 0) outIdx[row] = (float)k;
  }
#pragma unroll
  for (int off = 32; off >= 1; off >>= 1) {
    cs += __shfl_xor(cs, off);
    rsum += __shfl_xor(rsum, off);
  }
  __shared__ float rc[4], rr[4];
  if (lane == 0) { rc[wid] = cs; rr[wid] = rsum; }
  __syncthreads();
  if (t == 0) {
    partCo[pb + blockIdx.x] = rc[0] + rc[1] + rc[2] + rc[3];
    partRe[pb + blockIdx.x] = rr[0] + rr[1] + rr[2] + rr[3];
  }
}

__global__ void zero_kernel(int* __restrict__ cnts) {
  if (threadIdx.x < 32) cnts[threadIdx.x] = 0;
}

__global__ __launch_bounds__(256) void finalize_kernel(
    const float* __restrict__ partRe, const float* __restrict__ partCo,
    float* __restrict__ out) {
  int t = threadIdx.x;
  float sr = 0.f, sc = 0.f;
  for (int i = t; i < 4096; i += 256) { sr += partRe[i]; sc += partCo[i]; }
#pragma unroll
  for (int off = 32; off >= 1; off >>= 1) {
    sr += __shfl_xor(sr, off);
    sc += __shfl_xor(sc, off);
  }
  __shared__ float rs_[4], cs_[4];
  int wid = t >> 6, lane = t & 63;
  if (lane == 0) { rs_[wid] = sr; cs_[wid] = sc; }
  __syncthreads();
  if (t == 0) {
    float r = rs_[0] + rs_[1] + rs_[2] + rs_[3];
    float c = cs_[0] + cs_[1] + cs_[2] + cs_[3];
    out[0] = r / (65536.0f * 32.0f);
    float cl = c / (65536.0f * 256.0f);
    out[1] = cl;
    out[2] = cl;
  }
}

extern "C" void kernel_launch(void* const* d_in, const int* in_sizes, int n_in,
                              void* d_out, int out_size, void* d_ws,
                              size_t ws_size, hipStream_t stream) {
  const float* action = (const float*)d_in[0];
  const float* dimw = (const float*)d_in[1];
  const float* ew0 = (const float*)d_in[2];
  const float* eb0 = (const float*)d_in[3];
  const float* ew1 = (const float*)d_in[4];
  const float* eb1 = (const float*)d_in[5];
  const float* ew2 = (const float*)d_in[6];
  const float* eb2 = (const float*)d_in[7];
  const float* dw0 = (const float*)d_in[8];
  const float* db0 = (const float*)d_in[9];
  const float* dw1 = (const float*)d_in[10];
  const float* db1 = (const float*)d_in[11];
  const float* dw2 = (const float*)d_in[12];
  const float* db2 = (const float*)d_in[13];
  const float* cb = (const float*)d_in[14];
  float* out = (float*)d_out;
  char* ws = (char*)d_ws;

  const size_t fixed_b = 1048576 + 4096 + 1048576 + 3145728 + 1572864 +
                         4194304 + 2097152 + 131072 + 256 + 32768;
  // per-row: P0 3072 (e0 planes / z_e) + P1 4096 (e1) + 76 misc
  int R = N_ROWS;
  while (R > 2048) {
    if (fixed_b + (size_t)R * 7244 + 65536 <= ws_size) break;
    R >>= 1;
  }

  size_t off = 0;
  float* cbn = (float*)(ws + off); off += 1048576;
  float* cb2 = (float*)(ws + off); off += 4096;
  unsigned short* cbf = (unsigned short*)(ws + off); off += 1048576;
  unsigned short* ewf1 = (unsigned short*)(ws + off); off += 3145728;
  unsigned short* ewf2 = (unsigned short*)(ws + off); off += 1572864;
  float* T0 = (float*)(ws + off); off += 4194304;
  float* T1d = (float*)(ws + off); off += 2097152;
  float* T2d = (float*)(ws + off); off += 131072;
  int* fixcnts = (int*)(ws + off); off += 256;
  float* partRe = (float*)(ws + off); off += 16384;
  float* partCo = (float*)(ws + off); off += 16384;
  float* ze2 = (float*)(ws + off); off += (size_t)R * 4;
  int* idxc = (int*)(ws + off); off += (size_t)R * 4;
  int* fixlist = (int*)(ws + off); off += (size_t)R * 4;
  float* fixbv = (float*)(ws + off); off += (size_t)R * 32;
  int* fixbc = (int*)(ws + off); off += (size_t)R * 32;
  char* P0 = ws + off; off += (size_t)R * 3072;
  char* P1 = ws + off; off += (size_t)R * 4096;

  unsigned short* e0p = (unsigned short*)P0;  // 3 planes, stride R*512 shorts
  size_t aps0 = (size_t)R * 512;
  float* e1 = (float*)P1;                     // R x 1024 f32
  float* z_e = (float*)P0;                    // aliases e0p (dead after enc1)

  zero_kernel<<<1, 64, 0, stream>>>(fixcnts);
  rownorm_kernel<<<256, 256, 0, stream>>>(cb, cbn, cb2);
  frag_pack2_t<<<dim3(64, 8), 64, 0, stream>>>(cbn, cbf);
  frag_pack_kernel<<<dim3(64, 16), 64, 0, stream>>>(ew1, ewf1, 512, 1024);
  frag_pack_kernel<<<dim3(16, 32), 64, 0, stream>>>(ew2, ewf2, 1024, 256);

  // decoder table precompute: T2[k] = dec(cbn[k]) (fp32)
  gemm64_kernel<true><<<dim3(16, 16), 256, 0, stream>>>(cbn, dw0, db0, T0, 256, 1024);
  gemm64_kernel<true><<<dim3(8, 16), 256, 0, stream>>>(T0, dw1, db1, T1d, 1024, 512);
  t2_kernel<<<128, 256, 0, stream>>>(T1d, dw2, db2, T2d);

  for (int base = 0; base < N_ROWS; base += R) {
    int ci = base / R;
    const float* act_c = action + (size_t)base * 32;
    float* out_c = out + (size_t)base * 32;
    int* fixcnt = &fixcnts[ci];

    // enc0 -> pre-split 3-plane e0; enc1 MFMA (dbuf); enc2+norm (dbuf)
    gemm_enc0_split<<<dim3(4, R / 128), 256, 0, stream>>>(
        act_c, ew0, eb0, e0p, aps0, 32, 512);
    mfma3_gemm<true><<<dim3(8, R / 128), 256, 0, stream>>>(
        e0p, aps0, ewf1, eb1, e1, 512, 1024);
    mfma3_norm<<<R / 64, 256, 0, stream>>>(e1, ewf2, eb2, z_e, ze2);

    dist2_mfma<<<R / 64, 256, 0, stream>>>(z_e, cbf, idxc, fixcnt, fixlist);
    fixup_part<<<dim3(8, R / 128), 256, 0, stream>>>(
        z_e, cbn, ze2, cb2, fixlist, fixcnt, fixbv, fixbc);
    fixup_reduce<<<R / 256, 256, 0, stream>>>(fixbv, fixbc, fixlist, fixcnt,
                                              idxc);

    fused_tail<<<R / 16, 256, 0, stream>>>(
        z_e, cbn, idxc, T2d, act_c, dimw, partRe, partCo,
        out + 2097152 + base, out_c, base >> 4);
  }

  finalize_kernel<<<1, 256, 0, stream>>>(partRe, partCo, out + 2162688);
}